// Round 1
// baseline (372.242 us; speedup 1.0000x reference)
//
#include <hip/hip_runtime.h>
#include <math.h>

#define SAMPLE_THRESH 0.05f

// Bit-exact distance: explicit *_rn intrinsics are contraction barriers, so
// every kernel computes the identical fp32 bit pattern for D[i][j]. This is
// required because the mask tests exact equality (D == row_min) & (D == col_min).
__device__ __forceinline__ float dist_exact(float xa0, float xa1, float a2,
                                            float xb0, float xb1, float b2) {
    float p  = __fmul_rn(xa1, xb1);
    float q  = __fmaf_rn(xa0, xb0, p);      // dot(xa, xb)
    float s  = __fadd_rn(a2, b2);
    float d2 = __fmaf_rn(-2.0f, q, s);      // a2 + b2 - 2*dot
    d2 = fmaxf(d2, 1e-12f);
    return __fsqrt_rn(d2);
}

// Kernel A: grid_sample (bilinear, zeros padding, align_corners=False) of the
// flow channels (warp[...,2], warp[...,3]) and certainty at x_A; also b2 = |x_B|^2.
// Apack[i] = (fx, fy, a2, cert)
__global__ __launch_bounds__(256) void sample_kernel(
    const float* __restrict__ xA, const float* __restrict__ xB,
    const float4* __restrict__ warp, const float* __restrict__ cert,
    float4* __restrict__ Apack, float* __restrict__ b2arr,
    int nA, int nB, int H, int W) {
    int i = blockIdx.x * blockDim.x + threadIdx.x;
    if (i < nA) {
        float px = xA[2 * i + 0], py = xA[2 * i + 1];
        float xf = (px + 1.0f) * (0.5f * (float)W) - 0.5f;
        float yf = (py + 1.0f) * (0.5f * (float)H) - 0.5f;
        float x0f = floorf(xf), y0f = floorf(yf);
        float wx1 = xf - x0f, wy1 = yf - y0f;
        float wx0 = 1.0f - wx1, wy0 = 1.0f - wy1;
        int x0 = (int)x0f, y0 = (int)y0f;
        float fx = 0.0f, fy = 0.0f, cv = 0.0f;
        // Accumulate in the reference's term order: (x0,y0),(x0+1,y0),(x0,y0+1),(x0+1,y0+1)
#pragma unroll
        for (int dy = 0; dy < 2; ++dy) {
#pragma unroll
            for (int dx = 0; dx < 2; ++dx) {
                int xi = x0 + dx, yi = y0 + dy;
                float vm = (xi >= 0 && xi < W && yi >= 0 && yi < H) ? 1.0f : 0.0f;
                int xc = min(max(xi, 0), W - 1);
                int yc = min(max(yi, 0), H - 1);
                int idx = yc * W + xc;
                float4 wv = warp[idx];
                float  c  = cert[idx];
                float wgt = (dx ? wx1 : wx0) * (dy ? wy1 : wy0);
                fx += (wv.z * vm) * wgt;
                fy += (wv.w * vm) * wgt;
                cv += (c    * vm) * wgt;
            }
        }
        float a2 = fx * fx + fy * fy;
        Apack[i] = make_float4(fx, fy, a2, cv);
    }
    if (i < nB) {
        float b0 = xB[2 * i + 0], b1 = xB[2 * i + 1];
        b2arr[i] = b0 * b0 + b1 * b1;
    }
}

// Kernel B1: per-row min over j. One wave handles 4 rows (4x reuse of the
// streamed x_B/b2 data). rowpack[i] = (xa0, xa1, a2, cert>thresh ? row_min : -1)
__global__ __launch_bounds__(256) void rowmin_kernel(
    const float4* __restrict__ Apack, const float2* __restrict__ xB,
    const float* __restrict__ b2arr, float4* __restrict__ rowpack,
    int nA, int nB) {
    int wave = (int)((blockIdx.x * blockDim.x + threadIdx.x) >> 6);
    int lane = threadIdx.x & 63;
    int i0 = wave * 4;
    if (i0 >= nA) return;
    float4 A0 = Apack[i0 + 0], A1 = Apack[i0 + 1];
    float4 A2 = Apack[i0 + 2], A3 = Apack[i0 + 3];
    float m0 = 1e30f, m1 = 1e30f, m2 = 1e30f, m3 = 1e30f;
    for (int j = lane; j < nB; j += 64) {
        float2 b = xB[j];
        float bb = b2arr[j];
        m0 = fminf(m0, dist_exact(A0.x, A0.y, A0.z, b.x, b.y, bb));
        m1 = fminf(m1, dist_exact(A1.x, A1.y, A1.z, b.x, b.y, bb));
        m2 = fminf(m2, dist_exact(A2.x, A2.y, A2.z, b.x, b.y, bb));
        m3 = fminf(m3, dist_exact(A3.x, A3.y, A3.z, b.x, b.y, bb));
    }
#pragma unroll
    for (int o = 32; o; o >>= 1) {
        m0 = fminf(m0, __shfl_xor(m0, o, 64));
        m1 = fminf(m1, __shfl_xor(m1, o, 64));
        m2 = fminf(m2, __shfl_xor(m2, o, 64));
        m3 = fminf(m3, __shfl_xor(m3, o, 64));
    }
    if (lane == 0) {
        rowpack[i0 + 0] = make_float4(A0.x, A0.y, A0.z, (A0.w > SAMPLE_THRESH) ? m0 : -1.0f);
        rowpack[i0 + 1] = make_float4(A1.x, A1.y, A1.z, (A1.w > SAMPLE_THRESH) ? m1 : -1.0f);
        rowpack[i0 + 2] = make_float4(A2.x, A2.y, A2.z, (A2.w > SAMPLE_THRESH) ? m2 : -1.0f);
        rowpack[i0 + 3] = make_float4(A3.x, A3.y, A3.z, (A3.w > SAMPLE_THRESH) ? m3 : -1.0f);
    }
}

// Kernel B2: per-column min over i. One wave handles 4 columns.
// colpack[j] = (xb0, xb1, b2, col_min)
__global__ __launch_bounds__(256) void colmin_kernel(
    const float4* __restrict__ Apack, const float2* __restrict__ xB,
    const float* __restrict__ b2arr, float4* __restrict__ colpack,
    int nA, int nB) {
    int wave = (int)((blockIdx.x * blockDim.x + threadIdx.x) >> 6);
    int lane = threadIdx.x & 63;
    int j0 = wave * 4;
    if (j0 >= nB) return;
    float2 b0 = xB[j0 + 0], b1 = xB[j0 + 1], b2v = xB[j0 + 2], b3 = xB[j0 + 3];
    float bb0 = b2arr[j0 + 0], bb1 = b2arr[j0 + 1], bb2 = b2arr[j0 + 2], bb3 = b2arr[j0 + 3];
    float m0 = 1e30f, m1 = 1e30f, m2 = 1e30f, m3 = 1e30f;
    for (int i = lane; i < nA; i += 64) {
        float4 a = Apack[i];
        m0 = fminf(m0, dist_exact(a.x, a.y, a.z, b0.x, b0.y, bb0));
        m1 = fminf(m1, dist_exact(a.x, a.y, a.z, b1.x, b1.y, bb1));
        m2 = fminf(m2, dist_exact(a.x, a.y, a.z, b2v.x, b2v.y, bb2));
        m3 = fminf(m3, dist_exact(a.x, a.y, a.z, b3.x, b3.y, bb3));
    }
#pragma unroll
    for (int o = 32; o; o >>= 1) {
        m0 = fminf(m0, __shfl_xor(m0, o, 64));
        m1 = fminf(m1, __shfl_xor(m1, o, 64));
        m2 = fminf(m2, __shfl_xor(m2, o, 64));
        m3 = fminf(m3, __shfl_xor(m3, o, 64));
    }
    if (lane == 0) {
        colpack[j0 + 0] = make_float4(b0.x, b0.y, bb0, m0);
        colpack[j0 + 1] = make_float4(b1.x, b1.y, bb1, m1);
        colpack[j0 + 2] = make_float4(b2v.x, b2v.y, bb2, m2);
        colpack[j0 + 3] = make_float4(b3.x, b3.y, bb3, m3);
    }
}

// Kernel C: recompute D on the fly per 64x1024 tile (row/col packs in LDS),
// write where(mask, D, 0) with coalesced float4 stores. Write-bound: 256 MB.
#define TI 64
#define TJ 1024
__global__ __launch_bounds__(256) void out_kernel(
    const float4* __restrict__ rowpack, const float4* __restrict__ colpack,
    float* __restrict__ out, int N) {
    __shared__ float4 cp[TJ];
    __shared__ float4 rp[TI];
    int tid = threadIdx.x;
    int j0 = blockIdx.x * TJ;
    int i0 = blockIdx.y * TI;
    for (int k = tid; k < TJ; k += 256) cp[k] = colpack[j0 + k];
    if (tid < TI) rp[tid] = rowpack[i0 + tid];
    __syncthreads();
    float4 c0 = cp[tid * 4 + 0], c1 = cp[tid * 4 + 1];
    float4 c2 = cp[tid * 4 + 2], c3 = cp[tid * 4 + 3];
    size_t base = (size_t)i0 * (size_t)N + (size_t)j0 + (size_t)tid * 4;
    for (int r = 0; r < TI; ++r) {
        float4 a = rp[r];
        float d0 = dist_exact(a.x, a.y, a.z, c0.x, c0.y, c0.z);
        float d1 = dist_exact(a.x, a.y, a.z, c1.x, c1.y, c1.z);
        float d2 = dist_exact(a.x, a.y, a.z, c2.x, c2.y, c2.z);
        float d3 = dist_exact(a.x, a.y, a.z, c3.x, c3.y, c3.z);
        float4 o;
        o.x = (d0 == a.w && d0 == c0.w) ? d0 : 0.0f;
        o.y = (d1 == a.w && d1 == c1.w) ? d1 : 0.0f;
        o.z = (d2 == a.w && d2 == c2.w) ? d2 : 0.0f;
        o.w = (d3 == a.w && d3 == c3.w) ? d3 : 0.0f;
        *(float4*)(out + base + (size_t)r * (size_t)N) = o;
    }
}

extern "C" void kernel_launch(void* const* d_in, const int* in_sizes, int n_in,
                              void* d_out, int out_size, void* d_ws, size_t ws_size,
                              hipStream_t stream) {
    const float* xA   = (const float*)d_in[0];
    const float* xB   = (const float*)d_in[1];
    const float* warp = (const float*)d_in[2];
    const float* cert = (const float*)d_in[3];
    int nA = in_sizes[0] / 2;   // 8192
    int nB = in_sizes[1] / 2;   // 8192
    const int H = 504, W = 1008;
    float* out = (float*)d_out;

    char* ws = (char*)d_ws;
    size_t oA   = 0;                                    // Apack: nA float4
    size_t oB2  = oA + (size_t)nA * sizeof(float4);     // b2:    nB float
    size_t oRow = (oB2 + (size_t)nB * sizeof(float) + 15) & ~(size_t)15; // rowpack
    size_t oCol = oRow + (size_t)nA * sizeof(float4);   // colpack
    float4* Apack   = (float4*)(ws + oA);
    float*  b2arr   = (float*)(ws + oB2);
    float4* rowpack = (float4*)(ws + oRow);
    float4* colpack = (float4*)(ws + oCol);

    int nmax = nA > nB ? nA : nB;
    sample_kernel<<<(nmax + 255) / 256, 256, 0, stream>>>(
        xA, xB, (const float4*)warp, cert, Apack, b2arr, nA, nB, H, W);

    int rowWaves = nA / 4;
    rowmin_kernel<<<(rowWaves * 64 + 255) / 256, 256, 0, stream>>>(
        Apack, (const float2*)xB, b2arr, rowpack, nA, nB);

    int colWaves = nB / 4;
    colmin_kernel<<<(colWaves * 64 + 255) / 256, 256, 0, stream>>>(
        Apack, (const float2*)xB, b2arr, colpack, nA, nB);

    dim3 grid(nB / TJ, nA / TI);
    out_kernel<<<grid, 256, 0, stream>>>(rowpack, colpack, out, nB);
}

// Round 2
// 325.346 us; speedup vs baseline: 1.1441x; 1.1441x over previous
//
#include <hip/hip_runtime.h>
#include <math.h>

#define SAMPLE_THRESH 0.05f

// Bit-exact squared distance: explicit *_rn intrinsics are contraction
// barriers, so every kernel computes the identical fp32 bit pattern.
// The mask tests exact equality (D == row_min) & (D == col_min).
__device__ __forceinline__ float d2_exact(float xa0, float xa1, float a2,
                                          float xb0, float xb1, float b2) {
    float p  = __fmul_rn(xa1, xb1);
    float q  = __fmaf_rn(xa0, xb0, p);      // dot(xa, xb)
    float s  = __fadd_rn(a2, b2);
    return __fmaf_rn(-2.0f, q, s);          // a2 + b2 - 2*dot
}

// Correctly-rounded sqrt is monotone, so min_j D_j == D_from_d2(min_j d2_j)
// bit-exactly. This lets the min loops skip sqrt entirely.
__device__ __forceinline__ float D_from_d2(float d2) {
    return __fsqrt_rn(fmaxf(d2, 1e-12f));
}

// Kernel A: grid_sample (bilinear, zeros, align_corners=False) of the flow
// channels (warp[...,2], warp[...,3]) and certainty at x_A.
// Apack[i] = (fx, fy, a2, cert);  Bpack[j] = (bx, by, b2, 0)
__global__ __launch_bounds__(256) void sample_kernel(
    const float* __restrict__ xA, const float* __restrict__ xB,
    const float4* __restrict__ warp, const float* __restrict__ cert,
    float4* __restrict__ Apack, float4* __restrict__ Bpack,
    int nA, int nB, int H, int W) {
    int i = blockIdx.x * blockDim.x + threadIdx.x;
    if (i < nA) {
        float px = xA[2 * i + 0], py = xA[2 * i + 1];
        float xf = (px + 1.0f) * (0.5f * (float)W) - 0.5f;
        float yf = (py + 1.0f) * (0.5f * (float)H) - 0.5f;
        float x0f = floorf(xf), y0f = floorf(yf);
        float wx1 = xf - x0f, wy1 = yf - y0f;
        float wx0 = 1.0f - wx1, wy0 = 1.0f - wy1;
        int x0 = (int)x0f, y0 = (int)y0f;
        float fx = 0.0f, fy = 0.0f, cv = 0.0f;
#pragma unroll
        for (int dy = 0; dy < 2; ++dy) {
#pragma unroll
            for (int dx = 0; dx < 2; ++dx) {
                int xi = x0 + dx, yi = y0 + dy;
                float vm = (xi >= 0 && xi < W && yi >= 0 && yi < H) ? 1.0f : 0.0f;
                int xc = min(max(xi, 0), W - 1);
                int yc = min(max(yi, 0), H - 1);
                int idx = yc * W + xc;
                float4 wv = warp[idx];
                float  c  = cert[idx];
                float wgt = (dx ? wx1 : wx0) * (dy ? wy1 : wy0);
                fx += (wv.z * vm) * wgt;
                fy += (wv.w * vm) * wgt;
                cv += (c    * vm) * wgt;
            }
        }
        float a2 = fx * fx + fy * fy;
        Apack[i] = make_float4(fx, fy, a2, cv);
    }
    if (i < nB) {
        float b0 = xB[2 * i + 0], b1 = xB[2 * i + 1];
        Bpack[i] = make_float4(b0, b1, b0 * b0 + b1 * b1, 0.0f);
    }
}

// Fused row-min + col-min over d2 (sqrt hoisted out of the loop).
// Waves [0, nA/4)        : 4 rows each, streaming Bpack.
// Waves [nA/4, nA/4+nB/4): 4 cols each, streaming Apack.
// rowpack[i] = (xa0, xa1, a2, cert>thresh ? row_min_D : -1)
// colpack[j] = (xb0, xb1, b2, col_min_D)
__global__ __launch_bounds__(256) void min_kernel(
    const float4* __restrict__ Apack, const float4* __restrict__ Bpack,
    float4* __restrict__ rowpack, float4* __restrict__ colpack,
    int nA, int nB) {
    int gwave = (int)((blockIdx.x * blockDim.x + threadIdx.x) >> 6);
    int lane = threadIdx.x & 63;
    int nRowWaves = nA / 4;
    float m0 = 1e30f, m1 = 1e30f, m2 = 1e30f, m3 = 1e30f;
    if (gwave < nRowWaves) {
        int i0 = gwave * 4;
        float4 A0 = Apack[i0 + 0], A1 = Apack[i0 + 1];
        float4 A2 = Apack[i0 + 2], A3 = Apack[i0 + 3];
        for (int j = lane; j < nB; j += 64) {
            float4 b = Bpack[j];
            m0 = fminf(m0, d2_exact(A0.x, A0.y, A0.z, b.x, b.y, b.z));
            m1 = fminf(m1, d2_exact(A1.x, A1.y, A1.z, b.x, b.y, b.z));
            m2 = fminf(m2, d2_exact(A2.x, A2.y, A2.z, b.x, b.y, b.z));
            m3 = fminf(m3, d2_exact(A3.x, A3.y, A3.z, b.x, b.y, b.z));
        }
#pragma unroll
        for (int o = 32; o; o >>= 1) {
            m0 = fminf(m0, __shfl_xor(m0, o, 64));
            m1 = fminf(m1, __shfl_xor(m1, o, 64));
            m2 = fminf(m2, __shfl_xor(m2, o, 64));
            m3 = fminf(m3, __shfl_xor(m3, o, 64));
        }
        if (lane == 0) {
            rowpack[i0 + 0] = make_float4(A0.x, A0.y, A0.z, (A0.w > SAMPLE_THRESH) ? D_from_d2(m0) : -1.0f);
            rowpack[i0 + 1] = make_float4(A1.x, A1.y, A1.z, (A1.w > SAMPLE_THRESH) ? D_from_d2(m1) : -1.0f);
            rowpack[i0 + 2] = make_float4(A2.x, A2.y, A2.z, (A2.w > SAMPLE_THRESH) ? D_from_d2(m2) : -1.0f);
            rowpack[i0 + 3] = make_float4(A3.x, A3.y, A3.z, (A3.w > SAMPLE_THRESH) ? D_from_d2(m3) : -1.0f);
        }
    } else {
        int j0 = (gwave - nRowWaves) * 4;
        if (j0 >= nB) return;
        float4 B0 = Bpack[j0 + 0], B1 = Bpack[j0 + 1];
        float4 B2 = Bpack[j0 + 2], B3 = Bpack[j0 + 3];
        for (int i = lane; i < nA; i += 64) {
            float4 a = Apack[i];
            m0 = fminf(m0, d2_exact(a.x, a.y, a.z, B0.x, B0.y, B0.z));
            m1 = fminf(m1, d2_exact(a.x, a.y, a.z, B1.x, B1.y, B1.z));
            m2 = fminf(m2, d2_exact(a.x, a.y, a.z, B2.x, B2.y, B2.z));
            m3 = fminf(m3, d2_exact(a.x, a.y, a.z, B3.x, B3.y, B3.z));
        }
#pragma unroll
        for (int o = 32; o; o >>= 1) {
            m0 = fminf(m0, __shfl_xor(m0, o, 64));
            m1 = fminf(m1, __shfl_xor(m1, o, 64));
            m2 = fminf(m2, __shfl_xor(m2, o, 64));
            m3 = fminf(m3, __shfl_xor(m3, o, 64));
        }
        if (lane == 0) {
            colpack[j0 + 0] = make_float4(B0.x, B0.y, B0.z, D_from_d2(m0));
            colpack[j0 + 1] = make_float4(B1.x, B1.y, B1.z, D_from_d2(m1));
            colpack[j0 + 2] = make_float4(B2.x, B2.y, B2.z, D_from_d2(m2));
            colpack[j0 + 3] = make_float4(B3.x, B3.y, B3.z, D_from_d2(m3));
        }
    }
}

// Kernel C: recompute D on the fly per 64x1024 tile (row/col packs in LDS),
// write where(mask, D, 0) with coalesced float4 stores. Write-bound: 256 MB.
#define TI 64
#define TJ 1024
__global__ __launch_bounds__(256) void out_kernel(
    const float4* __restrict__ rowpack, const float4* __restrict__ colpack,
    float* __restrict__ out, int N) {
    __shared__ float4 cp[TJ];
    __shared__ float4 rp[TI];
    int tid = threadIdx.x;
    int j0 = blockIdx.x * TJ;
    int i0 = blockIdx.y * TI;
    for (int k = tid; k < TJ; k += 256) cp[k] = colpack[j0 + k];
    if (tid < TI) rp[tid] = rowpack[i0 + tid];
    __syncthreads();
    float4 c0 = cp[tid * 4 + 0], c1 = cp[tid * 4 + 1];
    float4 c2 = cp[tid * 4 + 2], c3 = cp[tid * 4 + 3];
    size_t base = (size_t)i0 * (size_t)N + (size_t)j0 + (size_t)tid * 4;
    for (int r = 0; r < TI; ++r) {
        float4 a = rp[r];
        float d0 = D_from_d2(d2_exact(a.x, a.y, a.z, c0.x, c0.y, c0.z));
        float d1 = D_from_d2(d2_exact(a.x, a.y, a.z, c1.x, c1.y, c1.z));
        float d2 = D_from_d2(d2_exact(a.x, a.y, a.z, c2.x, c2.y, c2.z));
        float d3 = D_from_d2(d2_exact(a.x, a.y, a.z, c3.x, c3.y, c3.z));
        float4 o;
        o.x = (d0 == a.w && d0 == c0.w) ? d0 : 0.0f;
        o.y = (d1 == a.w && d1 == c1.w) ? d1 : 0.0f;
        o.z = (d2 == a.w && d2 == c2.w) ? d2 : 0.0f;
        o.w = (d3 == a.w && d3 == c3.w) ? d3 : 0.0f;
        *(float4*)(out + base + (size_t)r * (size_t)N) = o;
    }
}

extern "C" void kernel_launch(void* const* d_in, const int* in_sizes, int n_in,
                              void* d_out, int out_size, void* d_ws, size_t ws_size,
                              hipStream_t stream) {
    const float* xA   = (const float*)d_in[0];
    const float* xB   = (const float*)d_in[1];
    const float* warp = (const float*)d_in[2];
    const float* cert = (const float*)d_in[3];
    int nA = in_sizes[0] / 2;   // 8192
    int nB = in_sizes[1] / 2;   // 8192
    const int H = 504, W = 1008;
    float* out = (float*)d_out;

    char* ws = (char*)d_ws;
    float4* Apack   = (float4*)ws;
    float4* Bpack   = Apack + nA;
    float4* rowpack = Bpack + nB;
    float4* colpack = rowpack + nA;

    int nmax = nA > nB ? nA : nB;
    sample_kernel<<<(nmax + 255) / 256, 256, 0, stream>>>(
        xA, xB, (const float4*)warp, cert, Apack, Bpack, nA, nB, H, W);

    int totWaves = nA / 4 + nB / 4;
    min_kernel<<<(totWaves * 64 + 255) / 256, 256, 0, stream>>>(
        Apack, Bpack, rowpack, colpack, nA, nB);

    dim3 grid(nB / TJ, nA / TI);
    out_kernel<<<grid, 256, 0, stream>>>(rowpack, colpack, out, nB);
}